// Round 10
// baseline (329.848 us; speedup 1.0000x reference)
//
#include <hip/hip_runtime.h>
#include <math.h>

// CapsuleLayer routing on MI355X (gfx950). fp32 in/out.
// B=64, n=2048, k=32, in_C=16, out_C=32, 3 routing iterations.
//
// Round-20: round-9 byte-identical EXCEPT __launch_bounds__(1024, 1) on
// pass0_fused / fused_pass. Evidence: round-5's fused_pass (the only
// round where one made top-5) showed WRITE=290MB vs ~80MB legit at
// VGPR=64 -> ~210MB scratch spill/fill per pass. The loop's live set is
// ~110 VGPR (c0/c1=32, sa=32, orp=16, prefetch+addr~25); the default
// allocator heuristic targeted 8 waves/SIMD (V<=64 -- pointless for a
// 1024-thread block that can only ever fit 1/CU) and spilled the
// accumulators. (1024,1) raises the cap to 128 (4-waves/SIMD co-residency
// bound), fitting the live set with zero spill at UNCHANGED occupancy.
// Inverse of round-14's (1024,8) mistake. Falsifier: VGPR stays 64 or
// neutral total -> spill theory dead, barriers are the real stall.

#define BATCH 64
#define NN    2048
#define NK    32
#define NI    16
#define NO    32

#define PNB   16                  // nodes per fused block
#define NSETS (NN / PNB)          // 128 node-sets
#define NCH   4                   // reduce stage-A chunks
#define XT_JS 528                 // ushorts per node-row in xt_lds (32*16 + 16 pad)
#define XT0_JS 1040               // ushorts per node-row in pass0 xt (64*16 + 16 pad)

typedef __bf16 bf16x8 __attribute__((ext_vector_type(8)));
typedef float  f32x16 __attribute__((ext_vector_type(16)));

__device__ __forceinline__ unsigned short f2bf(float f) {
    unsigned int x = __float_as_uint(f);
    unsigned int lsb = (x >> 16) & 1u;
    x += 0x7fffu + lsb;                 // RNE
    return (unsigned short)(x >> 16);
}
__device__ __forceinline__ float bflo(unsigned int u) { return __uint_as_float(u << 16); }
__device__ __forceinline__ float bfhi(unsigned int u) { return __uint_as_float(u & 0xffff0000u); }

// ---------------- pass 0 + W transform (fused) ----------------
// Grid (128 sets, 2 k-halves), block 1024 = 16 waves. Wave w owns ONE
// k = khalf*16 + w, both b-halves (2 MFMAs). Per node: 8 coalesced fp32
// W loads per lane (fragment order), convert->bf16x8 A-frag, store wq
// bf16 (uint4) for passes 1/2, 2x MFMA vs x staged for all 64 b.
__global__ __launch_bounds__(1024, 1) void pass0_fused(
    const float* __restrict__ xg,            // fp32 [b][n][i]
    const float* __restrict__ Wg,            // fp32 [n][k][i][o]
    unsigned short* __restrict__ wq,         // bf16 [n][k][o][i] (written)
    float* __restrict__ part)                // fp32 [256 blk][k16][o][b64]
{
    __shared__ unsigned short xt_lds[PNB * XT0_JS];  // 33280 B

    const int tid   = threadIdx.x;
    const int w     = tid >> 6;                  // 0..15
    const int lane  = tid & 63;
    const int l5    = lane & 31;                 // b (local) / o for frag
    const int h5    = lane >> 5;                 // i-half
    const int set   = blockIdx.x;
    const int khalf = blockIdx.y;
    const int k     = khalf * 16 + w;
    const int nbase = set * PNB;

    // ---- stage x slice for ALL 64 b -> xt_lds (bf16 [j][b][i], padded) ----
#pragma unroll
    for (int rr = 0; rr < 4; ++rr) {
        const int id  = tid + rr * 1024;         // 0..4095
        const int bl  = id >> 6;                 // 0..63 b
        const int rem = id & 63;
        const int j   = rem >> 2;                // 0..15 node
        const int i4  = rem & 3;
        float4 v = *(const float4*)(xg + ((size_t)bl * NN + (nbase + j)) * NI + i4 * 4);
        ushort4 o4;
        o4.x = f2bf(v.x); o4.y = f2bf(v.y); o4.z = f2bf(v.z); o4.w = f2bf(v.w);
        *(ushort4*)(xt_lds + j * XT0_JS + bl * 16 + i4 * 4) = o4;
    }
    __syncthreads();

    float sa0[16], sa1[16];
#pragma unroll
    for (int r = 0; r < 16; ++r) { sa0[r] = 0.f; sa1[r] = 0.f; }

    for (int j = 0; j < PNB; ++j) {
        const int n = nbase + j;
        // W fragment: lane (o=l5, ih=h5) needs W[n][k][h5*8+jj][o], jj=0..7
        const float* wsrc = Wg + ((size_t)n * NK + k) * (NI * NO) + h5 * 8 * NO + l5;
        unsigned short us[8];
#pragma unroll
        for (int jj = 0; jj < 8; ++jj)
            us[jj] = f2bf(wsrc[jj * NO]);
        // store bf16 wq for passes 1/2 (same bytes wqt produced)
        *(uint4*)(wq + ((size_t)n * NK + k) * (NO * NI) + l5 * NI + h5 * 8) = *(uint4*)us;
        const bf16x8 bC = *(const bf16x8*)us;

        const bf16x8 aA = *(const bf16x8*)(xt_lds + j * XT0_JS + l5 * 16 + h5 * 8);
        const bf16x8 aB = *(const bf16x8*)(xt_lds + j * XT0_JS + 512 + l5 * 16 + h5 * 8);

        f32x16 c0, c1;
#pragma unroll
        for (int r = 0; r < 16; ++r) { c0[r] = 0.f; c1[r] = 0.f; }
        c0 = __builtin_amdgcn_mfma_f32_32x32x16_bf16(bC, aA, c0, 0, 0, 0);  // b-half 0
        c1 = __builtin_amdgcn_mfma_f32_32x32x16_bf16(bC, aB, c1, 0, 0, 0);  // b-half 1
#pragma unroll
        for (int r = 0; r < 16; ++r) { sa0[r] += c0[r]; sa1[r] += c1[r]; }
    }

    // ---- epilogue: partial [k16][o][b64], uniform probs scale 1/NK ----
    float* pb = part + ((size_t)(khalf * NSETS + set) << 15);
#pragma unroll
    for (int r = 0; r < 16; ++r) {
        const int o = (r & 3) + 8 * (r >> 2) + 4 * h5;
        pb[(w * NO + o) * 64 + l5]      = sa0[r] * (1.f / NK);
        pb[(w * NO + o) * 64 + 32 + l5] = sa1[r] * (1.f / NK);
    }
}

// ---------------- fused routing pass (PASS 1/2) ----------------
template <int PASS>
__global__ __launch_bounds__(1024, 1) void fused_pass(
    const float* __restrict__ xg,            // fp32 [b][n][i]
    const unsigned short* __restrict__ wq,   // bf16 [n][k][o][i]
    const float* __restrict__ vpart,         // fp32 [4][k][o][b] chunk sums
    float* __restrict__ logits0,             // fp32 [n][b][k]
    float* __restrict__ part)                // fp32 [256 blk][k][o][b32]
{
    __shared__ unsigned short xt_lds[PNB * XT_JS];   // 16896 B
    __shared__ float delta_lds[2][32 * 33];          // 8448 B

    const int tid  = threadIdx.x;
    const int w    = tid >> 6;                   // 0..15
    const int lane = tid & 63;
    const int l5   = lane & 31;                  // b (local) for MFMA cols
    const int h5   = lane >> 5;                  // o-half
    const int set  = blockIdx.x;
    const int hb   = blockIdx.y;
    const int k0   = 2 * w, k1 = 2 * w + 1;
    const int gb5  = hb * 32 + l5;               // global b for this lane
    const int sb   = tid >> 5;                   // softmax-phase local b
    const int sk   = tid & 31;                   // softmax-phase k
    const int nbase = set * PNB;

    // ---- stage x slice -> xt_lds (bf16 [j][b][i], padded rows) ----
#pragma unroll
    for (int rr = 0; rr < 2; ++rr) {
        const int id  = tid + rr * 1024;         // 0..2047
        const int bl  = id >> 6;                 // 0..31 local b
        const int rem = id & 63;
        const int j   = rem >> 2;                // 0..15 node
        const int i4  = rem & 3;
        float4 v = *(const float4*)(xg + ((size_t)(hb * 32 + bl) * NN + (nbase + j)) * NI + i4 * 4);
        ushort4 o4;
        o4.x = f2bf(v.x); o4.y = f2bf(v.y); o4.z = f2bf(v.z); o4.w = f2bf(v.w);
        *(ushort4*)(xt_lds + j * XT_JS + bl * 16 + i4 * 4) = o4;
    }
    __syncthreads();

    // out fragments, packed bf16 pairs (regs r, r+1): squash(sum_c vpart)
    unsigned orp0[8], orp1[8];
    {
        float v0[16], v1[16];
        float sq0 = 0.f, sq1 = 0.f;
#pragma unroll
        for (int r = 0; r < 16; ++r) {
            const int o = (r & 3) + 8 * (r >> 2) + 4 * h5;
            float a = 0.f, b = 0.f;
#pragma unroll
            for (int c = 0; c < NCH; ++c) {
                a += vpart[(((size_t)c * NK + k0) * NO + o) * BATCH + gb5];
                b += vpart[(((size_t)c * NK + k1) * NO + o) * BATCH + gb5];
            }
            v0[r] = a; v1[r] = b;
            sq0 = fmaf(a, a, sq0);
            sq1 = fmaf(b, b, sq1);
        }
        sq0 += __shfl_xor(sq0, 32);              // add other o-half
        sq1 += __shfl_xor(sq1, 32);
        const float cf0 = sq0 / ((1.f + sq0) * sqrtf(sq0));
        const float cf1 = sq1 / ((1.f + sq1) * sqrtf(sq1));
#pragma unroll
        for (int q = 0; q < 8; ++q) {
            orp0[q] = (unsigned)f2bf(v0[2 * q] * cf0) | ((unsigned)f2bf(v0[2 * q + 1] * cf0) << 16);
            orp1[q] = (unsigned)f2bf(v1[2 * q] * cf1) | ((unsigned)f2bf(v1[2 * q + 1] * cf1) << 16);
        }
    }

    float sa0[16], sa1[16];
#pragma unroll
    for (int r = 0; r < 16; ++r) { sa0[r] = 0.f; sa1[r] = 0.f; }

    // depth-1 prefetch of wq fragments (+ logits for PASS 2)
    bf16x8 b0N, b1N;
    float gN = 0.f;
    {
        const int n = nbase;
        b0N = *(const bf16x8*)(wq + (size_t)n * (NK * NO * NI) + k0 * (NO * NI) + l5 * NI + h5 * 8);
        b1N = *(const bf16x8*)(wq + (size_t)n * (NK * NO * NI) + k1 * (NO * NI) + l5 * NI + h5 * 8);
        if constexpr (PASS == 2)
            gN = logits0[(size_t)n * (BATCH * NK) + hb * 1024 + tid];
    }

    int buf = 0;
    for (int j = 0; j < PNB; ++j) {
        const int n = nbase + j;
        const bf16x8 b0C = b0N, b1C = b1N;
        const float gC = gN;
        if (j < PNB - 1) {
            const int n2 = n + 1;
            b0N = *(const bf16x8*)(wq + (size_t)n2 * (NK * NO * NI) + k0 * (NO * NI) + l5 * NI + h5 * 8);
            b1N = *(const bf16x8*)(wq + (size_t)n2 * (NK * NO * NI) + k1 * (NO * NI) + l5 * NI + h5 * 8);
            if constexpr (PASS == 2)
                gN = logits0[(size_t)n2 * (BATCH * NK) + hb * 1024 + tid];
        }
        const bf16x8 aC = *(const bf16x8*)(xt_lds + j * XT_JS + l5 * 16 + h5 * 8);

        f32x16 c0, c1;
#pragma unroll
        for (int r = 0; r < 16; ++r) { c0[r] = 0.f; c1[r] = 0.f; }
        c0 = __builtin_amdgcn_mfma_f32_32x32x16_bf16(b0C, aC, c0, 0, 0, 0);  // A=wq(k0), B=x
        c1 = __builtin_amdgcn_mfma_f32_32x32x16_bf16(b1C, aC, c1, 0, 0, 0);  // A=wq(k1), B=x

        // in-register delta dot (this lane's o-half), then cross-half sum
        float d0 = 0.f, d1 = 0.f;
#pragma unroll
        for (int r = 0; r < 16; ++r) {
            const unsigned u0 = orp0[r >> 1], u1 = orp1[r >> 1];
            const float o0 = (r & 1) ? bfhi(u0) : bflo(u0);
            const float o1 = (r & 1) ? bfhi(u1) : bflo(u1);
            d0 = fmaf(c0[r], o0, d0);
            d1 = fmaf(c1[r], o1, d1);
        }
        d0 += __shfl_xor(d0, 32);
        d1 += __shfl_xor(d1, 32);

        delta_lds[buf][l5 * 33 + (h5 ? k1 : k0)] = h5 ? d1 : d0;
        __syncthreads();

        // softmax phase: tid -> (sb, sk)
        float l = delta_lds[buf][sb * 33 + sk];
        if constexpr (PASS == 1)
            logits0[(size_t)n * (BATCH * NK) + hb * 1024 + tid] = l;   // coalesced
        else
            l += gC;
        float e = __expf(l);             // no max-subtraction: |l| <= ~8
        float s = e;
#pragma unroll
        for (int mask = 1; mask < 32; mask <<= 1)
            s += __shfl_xor(s, mask);
        delta_lds[buf][sb * 33 + sk] = e / s;    // own slot: no race
        __syncthreads();

        const float p0 = delta_lds[buf][l5 * 33 + k0];
        const float p1 = delta_lds[buf][l5 * 33 + k1];
#pragma unroll
        for (int r = 0; r < 16; ++r) {
            sa0[r] = fmaf(p0, c0[r], sa0[r]);
            sa1[r] = fmaf(p1, c1[r], sa1[r]);
        }
        buf ^= 1;
    }

    // ---- epilogue: coalesced private partial write (NO atomics) ----
    float* pb = part + ((size_t)(hb * NSETS + set) << 15);     // 32768 floats/blk
#pragma unroll
    for (int r = 0; r < 16; ++r) {
        const int o = (r & 3) + 8 * (r >> 2) + 4 * h5;
        pb[(k0 * NO + o) * 32 + l5] = sa0[r];
        pb[(k1 * NO + o) * 32 + l5] = sa1[r];
    }
}

// ---------------- reduce stage-A (passes 1/2 layout) ----------------
__global__ __launch_bounds__(1024) void reduce_stageA(
    const float* __restrict__ part,
    float* __restrict__ vpart)
{
    const int k  = blockIdx.x;
    const int hb = blockIdx.y;
    const int c  = blockIdx.z;
    const int t  = threadIdx.x;
    const int o  = t >> 5;
    const int b  = t & 31;

    const float* src = part + ((size_t)(hb * NSETS + c * (NSETS / NCH)) << 15)
                            + (k << 10) + (o << 5) + b;
    float v0 = 0.f, v1 = 0.f, v2 = 0.f, v3 = 0.f;
#pragma unroll 4
    for (int s = 0; s < NSETS / NCH; s += 4) {
        v0 += src[(size_t)(s + 0) << 15];
        v1 += src[(size_t)(s + 1) << 15];
        v2 += src[(size_t)(s + 2) << 15];
        v3 += src[(size_t)(s + 3) << 15];
    }
    vpart[(((size_t)c * NK + k) * NO + o) * BATCH + hb * 32 + b] = (v0 + v1) + (v2 + v3);
}

// ---------------- reduce stage-A0 (pass-0 k-split layout) ----------------
// part block (khalf,set) holds [k16][o32][b64]; entry for global k:
// khalf=k>>4, kk=k&15 at (kk*32+o)*64 + hb*32 + b.
__global__ __launch_bounds__(1024) void reduce_stageA0(
    const float* __restrict__ part,
    float* __restrict__ vpart)
{
    const int k  = blockIdx.x;
    const int hb = blockIdx.y;
    const int c  = blockIdx.z;
    const int t  = threadIdx.x;
    const int o  = t >> 5;
    const int b  = t & 31;
    const int khalf = k >> 4, kk = k & 15;

    const float* src = part + ((size_t)(khalf * NSETS + c * (NSETS / NCH)) << 15)
                            + ((kk * NO + o) << 6) + hb * 32 + b;
    float v0 = 0.f, v1 = 0.f, v2 = 0.f, v3 = 0.f;
#pragma unroll 4
    for (int s = 0; s < NSETS / NCH; s += 4) {
        v0 += src[(size_t)(s + 0) << 15];
        v1 += src[(size_t)(s + 1) << 15];
        v2 += src[(size_t)(s + 2) << 15];
        v3 += src[(size_t)(s + 3) << 15];
    }
    vpart[(((size_t)c * NK + k) * NO + o) * BATCH + hb * 32 + b] = (v0 + v1) + (v2 + v3);
}

// ---------------- final: sum chunks + squash -> outp ----------------
__global__ __launch_bounds__(1024) void reduce_final(
    const float* __restrict__ vpart,
    float* __restrict__ outp)
{
    __shared__ float s_lds[32 * 33];
    __shared__ float cf_lds[32];
    const int k  = blockIdx.x;
    const int hb = blockIdx.y;
    const int t  = threadIdx.x;
    const int o  = t >> 5;
    const int b  = t & 31;

    float v = 0.f;
#pragma unroll
    for (int c = 0; c < NCH; ++c)
        v += vpart[(((size_t)c * NK + k) * NO + o) * BATCH + hb * 32 + b];
    s_lds[o * 33 + b] = v;
    __syncthreads();
    if (t < 32) {
        float sq = 0.f;
#pragma unroll
        for (int oo = 0; oo < 32; ++oo) { const float x = s_lds[oo * 33 + t]; sq = fmaf(x, x, sq); }
        cf_lds[t] = sq / ((1.f + sq) * sqrtf(sq));
    }
    __syncthreads();
    const int bq = t >> 5, oq = t & 31;              // remap for coalesced out
    outp[(size_t)(hb * 32 + bq) * 1024 + k * 32 + oq] = s_lds[oq * 33 + bq] * cf_lds[bq];
}

// ---------------- legacy fallback (round-2 code, known-good 582 us) ----------------

#define LBB 32
#define LNCHUNK 8
#define LNBLK (NN / LNCHUNK)
#define LTHREADS 512
#define WK_STRIDE 516

template <int PASS>
__global__ __launch_bounds__(LTHREADS, 1) void legacy_pass(
    const float* __restrict__ xg, const float* __restrict__ Wg,
    const float* __restrict__ outvL, float* __restrict__ logits,
    float* __restrict__ partial)
{
    __shared__ float w_lds[NK * WK_STRIDE];
    __shared__ float x_lds[LBB][NI + 1];
    __shared__ float delta_lds[LBB][NK + 1];
    const int t = threadIdx.x, nb = blockIdx.x, bg = blockIdx.y;
    const int b0 = bg * LBB;
    const int k = t >> 4, bq = t & 15, bl0 = bq * 2, bl1 = bq * 2 + 1;
    float acc0[NO], acc1[NO];
#pragma unroll
    for (int o = 0; o < NO; ++o) { acc0[o] = 0.f; acc1[o] = 0.f; }
    float outr0[NO], outr1[NO];
    if constexpr (PASS >= 1) {
        const float4* o0 = (const float4*)&outvL[((b0 + bl0) * NK + k) * NO];
        const float4* o1 = (const float4*)&outvL[((b0 + bl1) * NK + k) * NO];
#pragma unroll
        for (int q = 0; q < NO / 4; ++q) {
            float4 a = o0[q]; float4 b = o1[q];
            outr0[4*q+0]=a.x; outr0[4*q+1]=a.y; outr0[4*q+2]=a.z; outr0[4*q+3]=a.w;
            outr1[4*q+0]=b.x; outr1[4*q+1]=b.y; outr1[4*q+2]=b.z; outr1[4*q+3]=b.w;
        }
    }
    for (int j = 0; j < LNCHUNK; ++j) {
        const int n = nb * LNCHUNK + j;
        __syncthreads();
        {
            const float4* src = (const float4*)(Wg + (size_t)n * (NK * NI * NO));
#pragma unroll
            for (int r = 0; r < (NK * NI * NO / 4) / LTHREADS; ++r) {
                int idx4 = t + r * LTHREADS;
                float4 v = src[idx4];
                int e = idx4 * 4, kk = e >> 9, rem = e & 511;
                *(float4*)&w_lds[kk * WK_STRIDE + rem] = v;
            }
        }
        { int bl = t >> 4, i = t & 15;
          x_lds[bl][i] = xg[((size_t)(b0 + bl) * NN + n) * NI + i]; }
        __syncthreads();
        if constexpr (PASS == 0) {
#pragma unroll
            for (int i = 0; i < NI; ++i) {
                float xa = x_lds[bl0][i], xb = x_lds[bl1][i];
                const float* wrow = &w_lds[k * WK_STRIDE + i * NO];
#pragma unroll
                for (int o = 0; o < NO; ++o) {
                    float w = wrow[o];
                    acc0[o] = fmaf(xa, w, acc0[o]);
                    acc1[o] = fmaf(xb, w, acc1[o]);
                }
            }
        } else {
            float pr0[NO], pr1[NO];
#pragma unroll
            for (int o = 0; o < NO; ++o) { pr0[o] = 0.f; pr1[o] = 0.f; }
#pragma unroll
            for (int i = 0; i < NI; ++i) {
                float xa = x_lds[bl0][i], xb = x_lds[bl1][i];
                const float* wrow = &w_lds[k * WK_STRIDE + i * NO];
#pragma unroll
                for (int o = 0; o < NO; ++o) {
                    float w = wrow[o];
                    pr0[o] = fmaf(xa, w, pr0[o]);
                    pr1[o] = fmaf(xb, w, pr1[o]);
                }
            }
            float d0 = 0.f, d1 = 0.f;
#pragma unroll
            for (int o = 0; o < NO; ++o) {
                d0 = fmaf(pr0[o], outr0[o], d0);
                d1 = fmaf(pr1[o], outr1[o], d1);
            }
            float l0 = d0, l1 = d1;
            const size_t li0 = ((size_t)(b0 + bl0) * NN + n) * NK + k;
            const size_t li1 = ((size_t)(b0 + bl1) * NN + n) * NK + k;
            if constexpr (PASS == 2) { l0 += logits[li0]; l1 += logits[li1]; }
            else { logits[li0] = d0; logits[li1] = d1; }
            delta_lds[bl0][k] = l0; delta_lds[bl1][k] = l1;
            __syncthreads();
            float m0 = -1e30f, m1 = -1e30f;
#pragma unroll
            for (int kk = 0; kk < NK; ++kk) {
                m0 = fmaxf(m0, delta_lds[bl0][kk]);
                m1 = fmaxf(m1, delta_lds[bl1][kk]);
            }
            float s0 = 0.f, s1 = 0.f;
#pragma unroll
            for (int kk = 0; kk < NK; ++kk) {
                s0 += __expf(delta_lds[bl0][kk] - m0);
                s1 += __expf(delta_lds[bl1][kk] - m1);
            }
            float p0 = __expf(l0 - m0) / s0;
            float p1 = __expf(l1 - m1) / s1;
#pragma unroll
            for (int o = 0; o < NO; ++o) {
                acc0[o] = fmaf(p0, pr0[o], acc0[o]);
                acc1[o] = fmaf(p1, pr1[o], acc1[o]);
            }
        }
    }
    const float scale = (PASS == 0) ? (1.f / NK) : 1.f;
    float4* p0 = (float4*)&partial[(((size_t)nb * BATCH + (b0 + bl0)) * NK + k) * NO];
    float4* p1 = (float4*)&partial[(((size_t)nb * BATCH + (b0 + bl1)) * NK + k) * NO];
#pragma unroll
    for (int q = 0; q < NO / 4; ++q) {
        float4 v0, v1;
        v0.x = acc0[4*q+0]*scale; v0.y = acc0[4*q+1]*scale;
        v0.z = acc0[4*q+2]*scale; v0.w = acc0[4*q+3]*scale;
        v1.x = acc1[4*q+0]*scale; v1.y = acc1[4*q+1]*scale;
        v1.z = acc1[4*q+2]*scale; v1.w = acc1[4*q+3]*scale;
        p0[q] = v0; p1[q] = v1;
    }
}

__global__ __launch_bounds__(256) void legacy_reduce(
    const float* __restrict__ partial, float* __restrict__ outf)
{
    const int tid = blockIdx.x * 256 + threadIdx.x;
    float v = 0.f;
    for (int nb = 0; nb < LNBLK; ++nb)
        v += partial[(size_t)nb * (BATCH * NK * NO) + tid];
    float sq = v * v;
#pragma unroll
    for (int off = 1; off < 32; off <<= 1) sq += __shfl_xor(sq, off);
    float coef = sq / ((1.f + sq) * sqrtf(sq));
    outf[tid] = v * coef;
}

// ---------------- launch ----------------

extern "C" void kernel_launch(void* const* d_in, const int* in_sizes, int n_in,
                              void* d_out, int out_size, void* d_ws, size_t ws_size,
                              hipStream_t stream)
{
    const float* xg = (const float*)d_in[0];
    const float* Wg = (const float*)d_in[1];
    float* outp = (float*)d_out;
    char* ws = (char*)d_ws;

    const size_t SZ_WQ     = (size_t)NN * NK * NO * NI * 2;          //  64 MiB
    const size_t SZ_PART   = (size_t)256 * 32768 * 4;                //  32 MiB
    const size_t SZ_LOGITS = (size_t)NN * BATCH * NK * 4;            //  16 MiB
    const size_t SZ_VPART  = (size_t)NCH * NK * NO * BATCH * 4;      //   1 MiB
    const size_t NEED = SZ_WQ + SZ_PART + SZ_LOGITS + SZ_VPART;

    if (ws_size >= NEED) {
        unsigned short* wq = (unsigned short*)ws;
        float* part    = (float*)(ws + SZ_WQ);
        float* logits0 = (float*)(ws + SZ_WQ + SZ_PART);
        float* vpart   = (float*)(ws + SZ_WQ + SZ_PART + SZ_LOGITS);

        dim3 pg(NSETS, 2);
        dim3 ra(NK, 2, NCH);
        dim3 fg(NK, 2);
        pass0_fused<<<pg, 1024, 0, stream>>>(xg, Wg, wq, part);
        reduce_stageA0<<<ra, 1024, 0, stream>>>(part, vpart);
        fused_pass<1><<<pg, 1024, 0, stream>>>(xg, wq, vpart, logits0, part);
        reduce_stageA<<<ra, 1024, 0, stream>>>(part, vpart);
        fused_pass<2><<<pg, 1024, 0, stream>>>(xg, wq, vpart, logits0, part);
        reduce_stageA<<<ra, 1024, 0, stream>>>(part, vpart);
        reduce_final<<<fg, 1024, 0, stream>>>(vpart, outp);
    } else {
        float* partial = (float*)ws;
        float* logits = (float*)(ws + (size_t)LNBLK * BATCH * NK * NO * 4);
        float* outvL = (float*)(ws + (size_t)LNBLK * BATCH * NK * NO * 4 + (size_t)BATCH * NN * NK * 4);
        dim3 grid(LNBLK, BATCH / LBB);
        const int rblocks = BATCH * NK * NO / 256;
        legacy_pass<0><<<grid, LTHREADS, 0, stream>>>(xg, Wg, nullptr, logits, partial);
        legacy_reduce<<<rblocks, 256, 0, stream>>>(partial, outvL);
        legacy_pass<1><<<grid, LTHREADS, 0, stream>>>(xg, Wg, outvL, logits, partial);
        legacy_reduce<<<rblocks, 256, 0, stream>>>(partial, outvL);
        legacy_pass<2><<<grid, LTHREADS, 0, stream>>>(xg, Wg, outvL, logits, partial);
        legacy_reduce<<<rblocks, 256, 0, stream>>>(partial, outp);
    }
}

// Round 11
// 320.865 us; speedup vs baseline: 1.0280x; 1.0280x over previous
//
#include <hip/hip_runtime.h>
#include <math.h>

// CapsuleLayer routing on MI355X (gfx950). fp32 in/out.
// B=64, n=2048, k=32, in_C=16, out_C=32, 3 routing iterations.
//
// Round-21: round-9 exact (322us, plain launch_bounds -- round-10's
// (1024,1) regressed to 330) + ONE change: depth-1 prefetch of the 8
// W fp32 loads in pass0_fused. Evidence (round-10 top-5): pass0 = 80us,
// HBM 27%, MfmaUtil 2%, VALU 6%, WRITE exactly legit (no spill) ->
// cleanly load-latency-bound; unlike fused_pass 1/2 (which prefetch wq),
// pass0 issued its 8 strided W loads and immediately waited on them
// every node. Prefetch node j+1's loads into fp32 regs before node j's
// convert/MFMA (+8 VGPR). Predicted: pass0 80 -> ~50-60us, total ~300.
// Falsifier: pass0 unchanged -> latency not the limiter -> next: LDS
// float4 staging of W.

#define BATCH 64
#define NN    2048
#define NK    32
#define NI    16
#define NO    32

#define PNB   16                  // nodes per fused block
#define NSETS (NN / PNB)          // 128 node-sets
#define NCH   4                   // reduce stage-A chunks
#define XT_JS 528                 // ushorts per node-row in xt_lds (32*16 + 16 pad)
#define XT0_JS 1040               // ushorts per node-row in pass0 xt (64*16 + 16 pad)

typedef __bf16 bf16x8 __attribute__((ext_vector_type(8)));
typedef float  f32x16 __attribute__((ext_vector_type(16)));

__device__ __forceinline__ unsigned short f2bf(float f) {
    unsigned int x = __float_as_uint(f);
    unsigned int lsb = (x >> 16) & 1u;
    x += 0x7fffu + lsb;                 // RNE
    return (unsigned short)(x >> 16);
}
__device__ __forceinline__ float bflo(unsigned int u) { return __uint_as_float(u << 16); }
__device__ __forceinline__ float bfhi(unsigned int u) { return __uint_as_float(u & 0xffff0000u); }

// ---------------- pass 0 + W transform (fused) ----------------
// Grid (128 sets, 2 k-halves), block 1024 = 16 waves. Wave w owns ONE
// k = khalf*16 + w, both b-halves (2 MFMAs). Per node: 8 coalesced fp32
// W loads per lane (fragment order, DEPTH-1 PREFETCHED), convert->bf16x8
// A-frag, store wq bf16 (uint4) for passes 1/2, 2x MFMA vs x staged for
// all 64 b. No barriers in the loop.
__global__ __launch_bounds__(1024) void pass0_fused(
    const float* __restrict__ xg,            // fp32 [b][n][i]
    const float* __restrict__ Wg,            // fp32 [n][k][i][o]
    unsigned short* __restrict__ wq,         // bf16 [n][k][o][i] (written)
    float* __restrict__ part)                // fp32 [256 blk][k16][o][b64]
{
    __shared__ unsigned short xt_lds[PNB * XT0_JS];  // 33280 B

    const int tid   = threadIdx.x;
    const int w     = tid >> 6;                  // 0..15
    const int lane  = tid & 63;
    const int l5    = lane & 31;                 // b (local) / o for frag
    const int h5    = lane >> 5;                 // i-half
    const int set   = blockIdx.x;
    const int khalf = blockIdx.y;
    const int k     = khalf * 16 + w;
    const int nbase = set * PNB;

    // ---- stage x slice for ALL 64 b -> xt_lds (bf16 [j][b][i], padded) ----
#pragma unroll
    for (int rr = 0; rr < 4; ++rr) {
        const int id  = tid + rr * 1024;         // 0..4095
        const int bl  = id >> 6;                 // 0..63 b
        const int rem = id & 63;
        const int j   = rem >> 2;                // 0..15 node
        const int i4  = rem & 3;
        float4 v = *(const float4*)(xg + ((size_t)bl * NN + (nbase + j)) * NI + i4 * 4);
        ushort4 o4;
        o4.x = f2bf(v.x); o4.y = f2bf(v.y); o4.z = f2bf(v.z); o4.w = f2bf(v.w);
        *(ushort4*)(xt_lds + j * XT0_JS + bl * 16 + i4 * 4) = o4;
    }
    __syncthreads();

    float sa0[16], sa1[16];
#pragma unroll
    for (int r = 0; r < 16; ++r) { sa0[r] = 0.f; sa1[r] = 0.f; }

    // depth-1 prefetch of the 8 W floats (fragment gather)
    float wf[8];
    {
        const float* wsrc = Wg + ((size_t)nbase * NK + k) * (NI * NO) + h5 * 8 * NO + l5;
#pragma unroll
        for (int jj = 0; jj < 8; ++jj)
            wf[jj] = wsrc[jj * NO];
    }

    for (int j = 0; j < PNB; ++j) {
        const int n = nbase + j;
        float wfn[8];
        if (j < PNB - 1) {
            const float* wsrcN = Wg + ((size_t)(n + 1) * NK + k) * (NI * NO) + h5 * 8 * NO + l5;
#pragma unroll
            for (int jj = 0; jj < 8; ++jj)
                wfn[jj] = wsrcN[jj * NO];
        }

        unsigned short us[8];
#pragma unroll
        for (int jj = 0; jj < 8; ++jj)
            us[jj] = f2bf(wf[jj]);
        // store bf16 wq for passes 1/2 (same bytes wqt produced)
        *(uint4*)(wq + ((size_t)n * NK + k) * (NO * NI) + l5 * NI + h5 * 8) = *(uint4*)us;
        const bf16x8 bC = *(const bf16x8*)us;

        const bf16x8 aA = *(const bf16x8*)(xt_lds + j * XT0_JS + l5 * 16 + h5 * 8);
        const bf16x8 aB = *(const bf16x8*)(xt_lds + j * XT0_JS + 512 + l5 * 16 + h5 * 8);

        f32x16 c0, c1;
#pragma unroll
        for (int r = 0; r < 16; ++r) { c0[r] = 0.f; c1[r] = 0.f; }
        c0 = __builtin_amdgcn_mfma_f32_32x32x16_bf16(bC, aA, c0, 0, 0, 0);  // b-half 0
        c1 = __builtin_amdgcn_mfma_f32_32x32x16_bf16(bC, aB, c1, 0, 0, 0);  // b-half 1
#pragma unroll
        for (int r = 0; r < 16; ++r) { sa0[r] += c0[r]; sa1[r] += c1[r]; }

        if (j < PNB - 1) {
#pragma unroll
            for (int jj = 0; jj < 8; ++jj)
                wf[jj] = wfn[jj];
        }
    }

    // ---- epilogue: partial [k16][o][b64], uniform probs scale 1/NK ----
    float* pb = part + ((size_t)(khalf * NSETS + set) << 15);
#pragma unroll
    for (int r = 0; r < 16; ++r) {
        const int o = (r & 3) + 8 * (r >> 2) + 4 * h5;
        pb[(w * NO + o) * 64 + l5]      = sa0[r] * (1.f / NK);
        pb[(w * NO + o) * 64 + 32 + l5] = sa1[r] * (1.f / NK);
    }
}

// ---------------- fused routing pass (PASS 1/2; round-9 exact) ----------------
template <int PASS>
__global__ __launch_bounds__(1024) void fused_pass(
    const float* __restrict__ xg,            // fp32 [b][n][i]
    const unsigned short* __restrict__ wq,   // bf16 [n][k][o][i]
    const float* __restrict__ vpart,         // fp32 [4][k][o][b] chunk sums
    float* __restrict__ logits0,             // fp32 [n][b][k]
    float* __restrict__ part)                // fp32 [256 blk][k][o][b32]
{
    __shared__ unsigned short xt_lds[PNB * XT_JS];   // 16896 B
    __shared__ float delta_lds[2][32 * 33];          // 8448 B

    const int tid  = threadIdx.x;
    const int w    = tid >> 6;                   // 0..15
    const int lane = tid & 63;
    const int l5   = lane & 31;                  // b (local) for MFMA cols
    const int h5   = lane >> 5;                  // o-half
    const int set  = blockIdx.x;
    const int hb   = blockIdx.y;
    const int k0   = 2 * w, k1 = 2 * w + 1;
    const int gb5  = hb * 32 + l5;               // global b for this lane
    const int sb   = tid >> 5;                   // softmax-phase local b
    const int sk   = tid & 31;                   // softmax-phase k
    const int nbase = set * PNB;

    // ---- stage x slice -> xt_lds (bf16 [j][b][i], padded rows) ----
#pragma unroll
    for (int rr = 0; rr < 2; ++rr) {
        const int id  = tid + rr * 1024;         // 0..2047
        const int bl  = id >> 6;                 // 0..31 local b
        const int rem = id & 63;
        const int j   = rem >> 2;                // 0..15 node
        const int i4  = rem & 3;
        float4 v = *(const float4*)(xg + ((size_t)(hb * 32 + bl) * NN + (nbase + j)) * NI + i4 * 4);
        ushort4 o4;
        o4.x = f2bf(v.x); o4.y = f2bf(v.y); o4.z = f2bf(v.z); o4.w = f2bf(v.w);
        *(ushort4*)(xt_lds + j * XT_JS + bl * 16 + i4 * 4) = o4;
    }
    __syncthreads();

    // out fragments, packed bf16 pairs (regs r, r+1): squash(sum_c vpart)
    unsigned orp0[8], orp1[8];
    {
        float v0[16], v1[16];
        float sq0 = 0.f, sq1 = 0.f;
#pragma unroll
        for (int r = 0; r < 16; ++r) {
            const int o = (r & 3) + 8 * (r >> 2) + 4 * h5;
            float a = 0.f, b = 0.f;
#pragma unroll
            for (int c = 0; c < NCH; ++c) {
                a += vpart[(((size_t)c * NK + k0) * NO + o) * BATCH + gb5];
                b += vpart[(((size_t)c * NK + k1) * NO + o) * BATCH + gb5];
            }
            v0[r] = a; v1[r] = b;
            sq0 = fmaf(a, a, sq0);
            sq1 = fmaf(b, b, sq1);
        }
        sq0 += __shfl_xor(sq0, 32);              // add other o-half
        sq1 += __shfl_xor(sq1, 32);
        const float cf0 = sq0 / ((1.f + sq0) * sqrtf(sq0));
        const float cf1 = sq1 / ((1.f + sq1) * sqrtf(sq1));
#pragma unroll
        for (int q = 0; q < 8; ++q) {
            orp0[q] = (unsigned)f2bf(v0[2 * q] * cf0) | ((unsigned)f2bf(v0[2 * q + 1] * cf0) << 16);
            orp1[q] = (unsigned)f2bf(v1[2 * q] * cf1) | ((unsigned)f2bf(v1[2 * q + 1] * cf1) << 16);
        }
    }

    float sa0[16], sa1[16];
#pragma unroll
    for (int r = 0; r < 16; ++r) { sa0[r] = 0.f; sa1[r] = 0.f; }

    // depth-1 prefetch of wq fragments (+ logits for PASS 2)
    bf16x8 b0N, b1N;
    float gN = 0.f;
    {
        const int n = nbase;
        b0N = *(const bf16x8*)(wq + (size_t)n * (NK * NO * NI) + k0 * (NO * NI) + l5 * NI + h5 * 8);
        b1N = *(const bf16x8*)(wq + (size_t)n * (NK * NO * NI) + k1 * (NO * NI) + l5 * NI + h5 * 8);
        if constexpr (PASS == 2)
            gN = logits0[(size_t)n * (BATCH * NK) + hb * 1024 + tid];
    }

    int buf = 0;
    for (int j = 0; j < PNB; ++j) {
        const int n = nbase + j;
        const bf16x8 b0C = b0N, b1C = b1N;
        const float gC = gN;
        if (j < PNB - 1) {
            const int n2 = n + 1;
            b0N = *(const bf16x8*)(wq + (size_t)n2 * (NK * NO * NI) + k0 * (NO * NI) + l5 * NI + h5 * 8);
            b1N = *(const bf16x8*)(wq + (size_t)n2 * (NK * NO * NI) + k1 * (NO * NI) + l5 * NI + h5 * 8);
            if constexpr (PASS == 2)
                gN = logits0[(size_t)n2 * (BATCH * NK) + hb * 1024 + tid];
        }
        const bf16x8 aC = *(const bf16x8*)(xt_lds + j * XT_JS + l5 * 16 + h5 * 8);

        f32x16 c0, c1;
#pragma unroll
        for (int r = 0; r < 16; ++r) { c0[r] = 0.f; c1[r] = 0.f; }
        c0 = __builtin_amdgcn_mfma_f32_32x32x16_bf16(b0C, aC, c0, 0, 0, 0);  // A=wq(k0), B=x
        c1 = __builtin_amdgcn_mfma_f32_32x32x16_bf16(b1C, aC, c1, 0, 0, 0);  // A=wq(k1), B=x

        // in-register delta dot (this lane's o-half), then cross-half sum
        float d0 = 0.f, d1 = 0.f;
#pragma unroll
        for (int r = 0; r < 16; ++r) {
            const unsigned u0 = orp0[r >> 1], u1 = orp1[r >> 1];
            const float o0 = (r & 1) ? bfhi(u0) : bflo(u0);
            const float o1 = (r & 1) ? bfhi(u1) : bflo(u1);
            d0 = fmaf(c0[r], o0, d0);
            d1 = fmaf(c1[r], o1, d1);
        }
        d0 += __shfl_xor(d0, 32);
        d1 += __shfl_xor(d1, 32);

        delta_lds[buf][l5 * 33 + (h5 ? k1 : k0)] = h5 ? d1 : d0;
        __syncthreads();

        // softmax phase: tid -> (sb, sk)
        float l = delta_lds[buf][sb * 33 + sk];
        if constexpr (PASS == 1)
            logits0[(size_t)n * (BATCH * NK) + hb * 1024 + tid] = l;   // coalesced
        else
            l += gC;
        float e = __expf(l);             // no max-subtraction: |l| <= ~8
        float s = e;
#pragma unroll
        for (int mask = 1; mask < 32; mask <<= 1)
            s += __shfl_xor(s, mask);
        delta_lds[buf][sb * 33 + sk] = e / s;    // own slot: no race
        __syncthreads();

        const float p0 = delta_lds[buf][l5 * 33 + k0];
        const float p1 = delta_lds[buf][l5 * 33 + k1];
#pragma unroll
        for (int r = 0; r < 16; ++r) {
            sa0[r] = fmaf(p0, c0[r], sa0[r]);
            sa1[r] = fmaf(p1, c1[r], sa1[r]);
        }
        buf ^= 1;
    }

    // ---- epilogue: coalesced private partial write (NO atomics) ----
    float* pb = part + ((size_t)(hb * NSETS + set) << 15);     // 32768 floats/blk
#pragma unroll
    for (int r = 0; r < 16; ++r) {
        const int o = (r & 3) + 8 * (r >> 2) + 4 * h5;
        pb[(k0 * NO + o) * 32 + l5] = sa0[r];
        pb[(k1 * NO + o) * 32 + l5] = sa1[r];
    }
}

// ---------------- reduce stage-A (passes 1/2 layout) ----------------
__global__ __launch_bounds__(1024) void reduce_stageA(
    const float* __restrict__ part,
    float* __restrict__ vpart)
{
    const int k  = blockIdx.x;
    const int hb = blockIdx.y;
    const int c  = blockIdx.z;
    const int t  = threadIdx.x;
    const int o  = t >> 5;
    const int b  = t & 31;

    const float* src = part + ((size_t)(hb * NSETS + c * (NSETS / NCH)) << 15)
                            + (k << 10) + (o << 5) + b;
    float v0 = 0.f, v1 = 0.f, v2 = 0.f, v3 = 0.f;
#pragma unroll 4
    for (int s = 0; s < NSETS / NCH; s += 4) {
        v0 += src[(size_t)(s + 0) << 15];
        v1 += src[(size_t)(s + 1) << 15];
        v2 += src[(size_t)(s + 2) << 15];
        v3 += src[(size_t)(s + 3) << 15];
    }
    vpart[(((size_t)c * NK + k) * NO + o) * BATCH + hb * 32 + b] = (v0 + v1) + (v2 + v3);
}

// ---------------- reduce stage-A0 (pass-0 k-split layout) ----------------
// part block (khalf,set) holds [k16][o32][b64]; entry for global k:
// khalf=k>>4, kk=k&15 at (kk*32+o)*64 + hb*32 + b.
__global__ __launch_bounds__(1024) void reduce_stageA0(
    const float* __restrict__ part,
    float* __restrict__ vpart)
{
    const int k  = blockIdx.x;
    const int hb = blockIdx.y;
    const int c  = blockIdx.z;
    const int t  = threadIdx.x;
    const int o  = t >> 5;
    const int b  = t & 31;
    const int khalf = k >> 4, kk = k & 15;

    const float* src = part + ((size_t)(khalf * NSETS + c * (NSETS / NCH)) << 15)
                            + ((kk * NO + o) << 6) + hb * 32 + b;
    float v0 = 0.f, v1 = 0.f, v2 = 0.f, v3 = 0.f;
#pragma unroll 4
    for (int s = 0; s < NSETS / NCH; s += 4) {
        v0 += src[(size_t)(s + 0) << 15];
        v1 += src[(size_t)(s + 1) << 15];
        v2 += src[(size_t)(s + 2) << 15];
        v3 += src[(size_t)(s + 3) << 15];
    }
    vpart[(((size_t)c * NK + k) * NO + o) * BATCH + hb * 32 + b] = (v0 + v1) + (v2 + v3);
}

// ---------------- final: sum chunks + squash -> outp ----------------
__global__ __launch_bounds__(1024) void reduce_final(
    const float* __restrict__ vpart,
    float* __restrict__ outp)
{
    __shared__ float s_lds[32 * 33];
    __shared__ float cf_lds[32];
    const int k  = blockIdx.x;
    const int hb = blockIdx.y;
    const int t  = threadIdx.x;
    const int o  = t >> 5;
    const int b  = t & 31;

    float v = 0.f;
#pragma unroll
    for (int c = 0; c < NCH; ++c)
        v += vpart[(((size_t)c * NK + k) * NO + o) * BATCH + hb * 32 + b];
    s_lds[o * 33 + b] = v;
    __syncthreads();
    if (t < 32) {
        float sq = 0.f;
#pragma unroll
        for (int oo = 0; oo < 32; ++oo) { const float x = s_lds[oo * 33 + t]; sq = fmaf(x, x, sq); }
        cf_lds[t] = sq / ((1.f + sq) * sqrtf(sq));
    }
    __syncthreads();
    const int bq = t >> 5, oq = t & 31;              // remap for coalesced out
    outp[(size_t)(hb * 32 + bq) * 1024 + k * 32 + oq] = s_lds[oq * 33 + bq] * cf_lds[bq];
}

// ---------------- legacy fallback (round-2 code, known-good 582 us) ----------------

#define LBB 32
#define LNCHUNK 8
#define LNBLK (NN / LNCHUNK)
#define LTHREADS 512
#define WK_STRIDE 516

template <int PASS>
__global__ __launch_bounds__(LTHREADS, 1) void legacy_pass(
    const float* __restrict__ xg, const float* __restrict__ Wg,
    const float* __restrict__ outvL, float* __restrict__ logits,
    float* __restrict__ partial)
{
    __shared__ float w_lds[NK * WK_STRIDE];
    __shared__ float x_lds[LBB][NI + 1];
    __shared__ float delta_lds[LBB][NK + 1];
    const int t = threadIdx.x, nb = blockIdx.x, bg = blockIdx.y;
    const int b0 = bg * LBB;
    const int k = t >> 4, bq = t & 15, bl0 = bq * 2, bl1 = bq * 2 + 1;
    float acc0[NO], acc1[NO];
#pragma unroll
    for (int o = 0; o < NO; ++o) { acc0[o] = 0.f; acc1[o] = 0.f; }
    float outr0[NO], outr1[NO];
    if constexpr (PASS >= 1) {
        const float4* o0 = (const float4*)&outvL[((b0 + bl0) * NK + k) * NO];
        const float4* o1 = (const float4*)&outvL[((b0 + bl1) * NK + k) * NO];
#pragma unroll
        for (int q = 0; q < NO / 4; ++q) {
            float4 a = o0[q]; float4 b = o1[q];
            outr0[4*q+0]=a.x; outr0[4*q+1]=a.y; outr0[4*q+2]=a.z; outr0[4*q+3]=a.w;
            outr1[4*q+0]=b.x; outr1[4*q+1]=b.y; outr1[4*q+2]=b.z; outr1[4*q+3]=b.w;
        }
    }
    for (int j = 0; j < LNCHUNK; ++j) {
        const int n = nb * LNCHUNK + j;
        __syncthreads();
        {
            const float4* src = (const float4*)(Wg + (size_t)n * (NK * NI * NO));
#pragma unroll
            for (int r = 0; r < (NK * NI * NO / 4) / LTHREADS; ++r) {
                int idx4 = t + r * LTHREADS;
                float4 v = src[idx4];
                int e = idx4 * 4, kk = e >> 9, rem = e & 511;
                *(float4*)&w_lds[kk * WK_STRIDE + rem] = v;
            }
        }
        { int bl = t >> 4, i = t & 15;
          x_lds[bl][i] = xg[((size_t)(b0 + bl) * NN + n) * NI + i]; }
        __syncthreads();
        if constexpr (PASS == 0) {
#pragma unroll
            for (int i = 0; i < NI; ++i) {
                float xa = x_lds[bl0][i], xb = x_lds[bl1][i];
                const float* wrow = &w_lds[k * WK_STRIDE + i * NO];
#pragma unroll
                for (int o = 0; o < NO; ++o) {
                    float w = wrow[o];
                    acc0[o] = fmaf(xa, w, acc0[o]);
                    acc1[o] = fmaf(xb, w, acc1[o]);
                }
            }
        } else {
            float pr0[NO], pr1[NO];
#pragma unroll
            for (int o = 0; o < NO; ++o) { pr0[o] = 0.f; pr1[o] = 0.f; }
#pragma unroll
            for (int i = 0; i < NI; ++i) {
                float xa = x_lds[bl0][i], xb = x_lds[bl1][i];
                const float* wrow = &w_lds[k * WK_STRIDE + i * NO];
#pragma unroll
                for (int o = 0; o < NO; ++o) {
                    float w = wrow[o];
                    pr0[o] = fmaf(xa, w, pr0[o]);
                    pr1[o] = fmaf(xb, w, pr1[o]);
                }
            }
            float d0 = 0.f, d1 = 0.f;
#pragma unroll
            for (int o = 0; o < NO; ++o) {
                d0 = fmaf(pr0[o], outr0[o], d0);
                d1 = fmaf(pr1[o], outr1[o], d1);
            }
            float l0 = d0, l1 = d1;
            const size_t li0 = ((size_t)(b0 + bl0) * NN + n) * NK + k;
            const size_t li1 = ((size_t)(b0 + bl1) * NN + n) * NK + k;
            if constexpr (PASS == 2) { l0 += logits[li0]; l1 += logits[li1]; }
            else { logits[li0] = d0; logits[li1] = d1; }
            delta_lds[bl0][k] = l0; delta_lds[bl1][k] = l1;
            __syncthreads();
            float m0 = -1e30f, m1 = -1e30f;
#pragma unroll
            for (int kk = 0; kk < NK; ++kk) {
                m0 = fmaxf(m0, delta_lds[bl0][kk]);
                m1 = fmaxf(m1, delta_lds[bl1][kk]);
            }
            float s0 = 0.f, s1 = 0.f;
#pragma unroll
            for (int kk = 0; kk < NK; ++kk) {
                s0 += __expf(delta_lds[bl0][kk] - m0);
                s1 += __expf(delta_lds[bl1][kk] - m1);
            }
            float p0 = __expf(l0 - m0) / s0;
            float p1 = __expf(l1 - m1) / s1;
#pragma unroll
            for (int o = 0; o < NO; ++o) {
                acc0[o] = fmaf(p0, pr0[o], acc0[o]);
                acc1[o] = fmaf(p1, pr1[o], acc1[o]);
            }
        }
    }
    const float scale = (PASS == 0) ? (1.f / NK) : 1.f;
    float4* p0 = (float4*)&partial[(((size_t)nb * BATCH + (b0 + bl0)) * NK + k) * NO];
    float4* p1 = (float4*)&partial[(((size_t)nb * BATCH + (b0 + bl1)) * NK + k) * NO];
#pragma unroll
    for (int q = 0; q < NO / 4; ++q) {
        float4 v0, v1;
        v0.x = acc0[4*q+0]*scale; v0.y = acc0[4*q+1]*scale;
        v0.z = acc0[4*q+2]*scale; v0.w = acc0[4*q+3]*scale;
        v1.x = acc1[4*q+0]*scale; v1.y = acc1[4*q+1]*scale;
        v1.z = acc1[4*q+2]*scale; v1.w = acc1[4*q+3]*scale;
        p0[q] = v0; p1[q] = v1;
    }
}

__global__ __launch_bounds__(256) void legacy_reduce(
    const float* __restrict__ partial, float* __restrict__ outf)
{
    const int tid = blockIdx.x * 256 + threadIdx.x;
    float v = 0.f;
    for (int nb = 0; nb < LNBLK; ++nb)
        v += partial[(size_t)nb * (BATCH * NK * NO) + tid];
    float sq = v * v;
#pragma unroll
    for (int off = 1; off < 32; off <<= 1) sq += __shfl_xor(sq, off);
    float coef = sq / ((1.f + sq) * sqrtf(sq));
    outf[tid] = v * coef;
}

// ---------------- launch ----------------

extern "C" void kernel_launch(void* const* d_in, const int* in_sizes, int n_in,
                              void* d_out, int out_size, void* d_ws, size_t ws_size,
                              hipStream_t stream)
{
    const float* xg = (const float*)d_in[0];
    const float* Wg = (const float*)d_in[1];
    float* outp = (float*)d_out;
    char* ws = (char*)d_ws;

    const size_t SZ_WQ     = (size_t)NN * NK * NO * NI * 2;          //  64 MiB
    const size_t SZ_PART   = (size_t)256 * 32768 * 4;                //  32 MiB
    const size_t SZ_LOGITS = (size_t)NN * BATCH * NK * 4;            //  16 MiB
    const size_t SZ_VPART  = (size_t)NCH * NK * NO * BATCH * 4;      //   1 MiB
    const size_t NEED = SZ_WQ + SZ_PART + SZ_LOGITS + SZ_VPART;

    if (ws_size >= NEED) {
        unsigned short* wq = (unsigned short*)ws;
        float* part    = (float*)(ws + SZ_WQ);
        float* logits0 = (float*)(ws + SZ_WQ + SZ_PART);
        float* vpart   = (float*)(ws + SZ_WQ + SZ_PART + SZ_LOGITS);

        dim3 pg(NSETS, 2);
        dim3 ra(NK, 2, NCH);
        dim3 fg(NK, 2);
        pass0_fused<<<pg, 1024, 0, stream>>>(xg, Wg, wq, part);
        reduce_stageA0<<<ra, 1024, 0, stream>>>(part, vpart);
        fused_pass<1><<<pg, 1024, 0, stream>>>(xg, wq, vpart, logits0, part);
        reduce_stageA<<<ra, 1024, 0, stream>>>(part, vpart);
        fused_pass<2><<<pg, 1024, 0, stream>>>(xg, wq, vpart, logits0, part);
        reduce_stageA<<<ra, 1024, 0, stream>>>(part, vpart);
        reduce_final<<<fg, 1024, 0, stream>>>(vpart, outp);
    } else {
        float* partial = (float*)ws;
        float* logits = (float*)(ws + (size_t)LNBLK * BATCH * NK * NO * 4);
        float* outvL = (float*)(ws + (size_t)LNBLK * BATCH * NK * NO * 4 + (size_t)BATCH * NN * NK * 4);
        dim3 grid(LNBLK, BATCH / LBB);
        const int rblocks = BATCH * NK * NO / 256;
        legacy_pass<0><<<grid, LTHREADS, 0, stream>>>(xg, Wg, nullptr, logits, partial);
        legacy_reduce<<<rblocks, 256, 0, stream>>>(partial, outvL);
        legacy_pass<1><<<grid, LTHREADS, 0, stream>>>(xg, Wg, outvL, logits, partial);
        legacy_reduce<<<rblocks, 256, 0, stream>>>(partial, outvL);
        legacy_pass<2><<<grid, LTHREADS, 0, stream>>>(xg, Wg, outvL, logits, partial);
        legacy_reduce<<<rblocks, 256, 0, stream>>>(partial, outp);
    }
}